// Round 18
// baseline (263.216 us; speedup 1.0000x reference)
//
#include <hip/hip_runtime.h>

typedef __attribute__((ext_vector_type(8))) __bf16 bf16x8;
typedef __attribute__((ext_vector_type(4))) float f32x4;
typedef __attribute__((ext_vector_type(8))) unsigned short ushort8;
typedef const __attribute__((address_space(1))) unsigned int gq_t;
typedef __attribute__((address_space(3))) unsigned int lq_t;

// RNE float -> bf16 (finite inputs)
__device__ __forceinline__ unsigned short f2bf(float f) {
  unsigned int u = __builtin_bit_cast(unsigned int, f);
  u += 0x7fffu + ((u >> 16) & 1u);
  return (unsigned short)(u >> 16);
}

// ------- fused convert: x -> bf16 and weight*scale -> bf16, one dispatch -------
__global__ void cvt_xw_kernel(const float* __restrict__ x, const float* __restrict__ w,
                              const float* __restrict__ scale,
                              ushort8* __restrict__ xa, ushort8* __restrict__ wb,
                              int n8x, int n8w, int k8) {
  int stride = gridDim.x * blockDim.x;
  int total = n8x + n8w;
  for (int i = blockIdx.x * blockDim.x + threadIdx.x; i < total; i += stride) {
    if (i < n8x) {
      const float4* p = (const float4*)(x) + 2 * (size_t)i;
      float4 v0 = p[0], v1 = p[1];
      ushort8 r;
      r[0] = f2bf(v0.x); r[1] = f2bf(v0.y); r[2] = f2bf(v0.z); r[3] = f2bf(v0.w);
      r[4] = f2bf(v1.x); r[5] = f2bf(v1.y); r[6] = f2bf(v1.z); r[7] = f2bf(v1.w);
      xa[i] = r;
    } else {
      int j = i - n8x;
      float s = scale[j / k8];
      const float4* p = (const float4*)(w) + 2 * (size_t)j;
      float4 v0 = p[0], v1 = p[1];
      ushort8 r;
      r[0] = f2bf(v0.x * s); r[1] = f2bf(v0.y * s); r[2] = f2bf(v0.z * s); r[3] = f2bf(v0.w * s);
      r[4] = f2bf(v1.x * s); r[5] = f2bf(v1.y * s); r[6] = f2bf(v1.z * s); r[7] = f2bf(v1.w * s);
      wb[j] = r;
    }
  }
}

// ========== 256x256 GEMM, 16 waves (64x64/wave) -> 4 waves/SIMD ==========
// C = A * B^T + bias.  A: bf16 [M][K], B: bf16 [N][K], C: fp32 [M][N].
// 16 waves (4 wr x 4 wc), BK=64, 128 KiB dynamic LDS.
//   buffer (64 KiB): [A0 16K: rows 0-127][A1: rows 128-255][BU0: cols 0-127][BU1: 128-255]
// Wave output 64x64: acc[4][4] = 64 VGPR -> total ~128/lane -> 4 waves/SIMD
// (2x the latency hiding of the 8-wave config whose 128-acc capped it at 2).
// R6/R13 4-barrier staggered schedule, halved per-wave: 4 ds_read + QUAD(8 MFMA)
// per phase; zigzag quadrants (0,n0)(0,n1)(1,n1)(1,n0); bg0 one-tile-ahead.
// Staging: 1 GL/unit (1024 thr x 16B = 16KB). Slot assignment (deadness-driven:
// A units are read EVERY phase -> A stages must be 1-tile-lead into ob):
//   P1: GL BU0(t+1)->ob   [old BU0(t-1) last read t-1.P2; >=3 barriers]
//   P2: GL A0(t+1)->ob, GL A1(t+1)->ob [old read t-1.P3; >=3 barriers]
//   P4: GL BU1(t+2)->cb   [cur.BU1 last read t.P2; >=2 barriers]
// vmcnt FIFO (1 load/unit): entry [BU1(t+1)]; +P1+P2x2+P4 -> 5; WAITV1 at P4
// retires exactly tile t+1's 4 units (distances 2-4 phases, proven regime);
// t==NT-2 -> WAITV0; t==NT-1 -> no-op.  LDB0(oth) at P4-post reads bg0(t+1).
// XOR swizzle byte ^= ((row&7)<<4): pre-swizzled global source + swizzled reads.
// global_load_lds offset immediate applies to LDS dest too -> ALWAYS offset=0;
// K-advance in 4 running pointers (pre-led 1 or 2 tiles), +64 elems/tile.

#define BARRIER asm volatile("s_barrier" ::: "memory")
#define WAITV1 asm volatile("s_waitcnt vmcnt(1)" ::: "memory")
#define WAITV0 asm volatile("s_waitcnt vmcnt(0)" ::: "memory")
#define GL(p, d) __builtin_amdgcn_global_load_lds((gq_t*)(p), (lq_t*)(d), 16, 0, 0)

// 8 MFMA: 2 mm x 2 nn x 2 kk
#define QUAD(MH, BG, NHB)                                                                \
  do {                                                                                   \
    __builtin_amdgcn_s_setprio(1);                                                       \
    _Pragma("unroll") for (int k_ = 0; k_ < 2; ++k_) {                                   \
      _Pragma("unroll") for (int mm = 0; mm < 2; ++mm) {                                 \
        _Pragma("unroll") for (int nn = 0; nn < 2; ++nn) {                               \
          acc[(MH)*2 + mm][(NHB)*2 + nn] = __builtin_amdgcn_mfma_f32_16x16x32_bf16(      \
              af[mm][k_], BG[nn][k_], acc[(MH)*2 + mm][(NHB)*2 + nn], 0, 0, 0);          \
        }                                                                                \
      }                                                                                  \
    }                                                                                    \
    __builtin_amdgcn_s_setprio(0);                                                       \
  } while (0)

#define TILE_BODY(T, CB)                                                                 \
  do {                                                                                   \
    const int t_ = (T);                                                                  \
    char* cur = lds + (CB) * 65536;                                                      \
    char* oth = lds + (((CB) ^ 1)) * 65536;                                              \
    /* P1: reads A-mh0 (4 ds_read) ; stages BU0(t+1) -> ob */                            \
    LDA(cur, 0);                                                                         \
    if (t_ + 1 < NT) GL(bP0, oth + 32768 + dstT);                                        \
    BARRIER; QUAD(0, bg0, 0);                                                            \
    /* P2: reads B-nh1 (4) ; stages A0(t+1), A1(t+1) -> ob */                            \
    LDB1(cur);                                                                           \
    if (t_ + 1 < NT) { GL(aP0, oth + dstT); GL(aP1, oth + 16384 + dstT); }               \
    BARRIER; QUAD(0, bg1, 1);                                                            \
    /* P3: reads A-mh1 (4) */                                                            \
    LDA(cur, 1);                                                                         \
    BARRIER; QUAD(1, bg1, 1);                                                            \
    /* P4: stages BU1(t+2) -> cb ; WAIT ; BAR ; QUAD ; LDB0(oth) one-ahead */            \
    if (t_ + 2 < NT) GL(bP1, cur + 49152 + dstT);                                        \
    if (t_ < NT - 2) { WAITV1; } else { WAITV0; }                                        \
    BARRIER; QUAD(1, bg0, 0);                                                            \
    if (t_ + 1 < NT) LDB0(oth);                                                          \
    aP0 += 64; aP1 += 64; bP0 += 64; bP1 += 64;                                          \
  } while (0)

__global__ __launch_bounds__(1024, 4) void gemm256_16w(
    const unsigned short* __restrict__ A, const unsigned short* __restrict__ B,
    const float* __restrict__ bias, float* __restrict__ C, int M, int N, int K) {
  extern __shared__ char lds[];

  const int nbn = N >> 8;
  const int nwg = (M >> 8) * nbn;
  int bid = blockIdx.x;
  if ((nwg & 7) == 0) {  // XCD-aware swizzle (bijective when nwg%8==0)
    int q = nwg >> 3;
    bid = (bid & 7) * q + (bid >> 3);
  }
  const int bm = (bid / nbn) << 8;   // ROW-major within chunk (col-major thrashes A in L2)
  const int bn = (bid % nbn) << 8;

  const int tid = threadIdx.x;
  const int lane = tid & 63;
  const int wid = tid >> 6;
  const int wr = wid >> 2;  // 0..3
  const int wc = wid & 3;   // 0..3
  const int NT = K >> 6;    // K-tiles of 64
  const int dstT = tid * 16;

  // ---- pre-swizzled global sources (linear LDS dest + inv-swz source) ----
  // unit phys row = tid>>3 (0..127) ; logical col = ((tid&7) ^ ((tid>>3)&7)) * 8 elems
  const int colel = (((tid & 7) ^ ((tid >> 3) & 7)) << 3);
  const unsigned short* aP0 = A + (size_t)(bm + (tid >> 3)) * K + colel;        // A0 rows 0-127
  const unsigned short* aP1 = aP0 + (size_t)128 * K;                            // A1 rows 128-255
  const unsigned short* bP0 = B + (size_t)(bn + (tid >> 3)) * K + colel;        // BU0 cols 0-127
  const unsigned short* bP1 = bP0 + (size_t)128 * K;                            // BU1 cols 128-255

  // ---- fragment read offsets (swizzled) ----
  const int i15 = lane & 15;
  const int qg = lane >> 4;
  const int swz = (lane & 7) << 4;
  const int colp0 = (qg << 4) ^ swz;
  const int colp1 = ((qg << 4) | 64) ^ swz;
  // wave A base: unit (wr>>1), local row (wr&1)*64 + mh*32 + mm*16 + i15
  const int aoff = (wr >> 1) * 16384 + (wr & 1) * 8192 + i15 * 128;
  // wave B base: unit (wc>>1), local col (wc&1)*64 + nh*32 + nn*16 + i15
  const int boff = 32768 + (wc >> 1) * 16384 + (wc & 1) * 8192 + i15 * 128;

  f32x4 acc[4][4];
#pragma unroll
  for (int m = 0; m < 4; ++m)
#pragma unroll
    for (int n = 0; n < 4; ++n) acc[m][n] = (f32x4){0.f, 0.f, 0.f, 0.f};

  bf16x8 af[2][2];   // current A half [mm][kk]
  bf16x8 bg0[2][2];  // n-half 0 fragments (read one tile ahead at P4-post)
  bf16x8 bg1[2][2];  // n-half 1 fragments (current tile)

  auto LDA = [&](const char* base, int mh) {
    const char* p = base + aoff + mh * 4096;
#pragma unroll
    for (int mm = 0; mm < 2; ++mm) {
      af[mm][0] = *(const bf16x8*)(p + mm * 2048 + colp0);
      af[mm][1] = *(const bf16x8*)(p + mm * 2048 + colp1);
    }
  };
  auto LDB0 = [&](const char* base) {  // n-half 0 -> bg0
    const char* p = base + boff;
#pragma unroll
    for (int nn = 0; nn < 2; ++nn) {
      bg0[nn][0] = *(const bf16x8*)(p + nn * 2048 + colp0);
      bg0[nn][1] = *(const bf16x8*)(p + nn * 2048 + colp1);
    }
  };
  auto LDB1 = [&](const char* base) {  // n-half 1 -> bg1
    const char* p = base + boff + 4096;
#pragma unroll
    for (int nn = 0; nn < 2; ++nn) {
      bg1[nn][0] = *(const bf16x8*)(p + nn * 2048 + colp0);
      bg1[nn][1] = *(const bf16x8*)(p + nn * 2048 + colp1);
    }
  };

  // ---- prologue: tile0's 4 units -> buf0, then BU1(1) -> buf1 ----
  GL(aP0, lds + dstT);               // A0(0)
  GL(bP0, lds + 32768 + dstT);       // BU0(0)
  GL(bP1, lds + 49152 + dstT);       // BU1(0)
  GL(aP1, lds + 16384 + dstT);       // A1(0)
  GL(bP1 + 64, lds + 65536 + 49152 + dstT);  // BU1(1)
  WAITV1;   // retire tile0's 4 units; BU1(1) stays in flight (= steady entry)
  BARRIER;  // tile0 stages visible to all waves
  LDB0(lds);  // bg0 <- buf0 n-half0 (tile0)
  // leads: BU0/A0/A1 staged next for tile1 (+64); BU1 for tile2 (+128)
  bP0 += 64; aP0 += 64; aP1 += 64;
  bP1 += 128;

  // ---- main loop: 2 tiles per iteration (compile-time buffer parity) ----
  for (int t = 0; t < NT; t += 2) {
    TILE_BODY(t, 0);
    TILE_BODY(t + 1, 1);
  }

  // ---- epilogue: C/D map col=lane&15, row=(lane>>4)*4+reg ----
  const int r0 = bm + wr * 64 + ((lane >> 4) << 2);
  const int c0 = bn + wc * 64 + (lane & 15);
  float bv[4];
#pragma unroll
  for (int n = 0; n < 4; ++n) bv[n] = bias[c0 + n * 16];
#pragma unroll
  for (int m = 0; m < 4; ++m) {
#pragma unroll
    for (int r = 0; r < 4; ++r) {
      float* crow = C + (size_t)(r0 + m * 16 + r) * N + c0;
#pragma unroll
      for (int n = 0; n < 4; ++n) crow[n * 16] = acc[m][n][r] + bv[n];
    }
  }
}

// ---------- fallback: fp32 tiled (odd shapes / tiny ws) ----------
__global__ void gemm_fallback_kernel(const float* __restrict__ X, const float* __restrict__ W,
                                     const float* __restrict__ scale, const float* __restrict__ bias,
                                     float* __restrict__ out, int M, int N, int K) {
  __shared__ float as[64][33];
  __shared__ float bs[64][33];
  int tx = threadIdx.x & 15, ty = threadIdx.x >> 4;
  int brow = blockIdx.y * 64, bcol = blockIdx.x * 64;
  float acc[4][4] = {};
  for (int k0 = 0; k0 < K; k0 += 32) {
    int kw = (K - k0 < 32) ? (K - k0) : 32;
    for (int i = 0; i < 8; ++i) {
      int idx = (int)threadIdx.x + i * 256;
      int r = idx >> 5, c = idx & 31;
      int ga = brow + r, gb = bcol + r;
      as[r][c] = (ga < M && c < kw) ? X[(size_t)ga * K + k0 + c] : 0.f;
      bs[r][c] = (gb < N && c < kw) ? W[(size_t)gb * K + k0 + c] * scale[gb] : 0.f;
    }
    __syncthreads();
    for (int k = 0; k < 32; ++k)
#pragma unroll
      for (int i = 0; i < 4; ++i)
#pragma unroll
        for (int j = 0; j < 4; ++j)
          acc[i][j] += as[ty * 4 + i][k] * bs[tx * 4 + j][k];
    __syncthreads();
  }
  for (int i = 0; i < 4; ++i) {
    int r = brow + ty * 4 + i;
    if (r >= M) continue;
    for (int j = 0; j < 4; ++j) {
      int c = bcol + tx * 4 + j;
      if (c < N) out[(size_t)r * N + c] = acc[i][j] + bias[c];
    }
  }
}

extern "C" void kernel_launch(void* const* d_in, const int* in_sizes, int n_in,
                              void* d_out, int out_size, void* d_ws, size_t ws_size,
                              hipStream_t stream) {
  const float* x     = (const float*)d_in[0];
  const float* w     = (const float*)d_in[1];
  const float* scale = (const float*)d_in[2];
  const float* bias  = (const float*)d_in[3];
  float* out = (float*)d_out;

  const long N = in_sizes[2];            // D_OUT
  const long K = in_sizes[1] / N;        // D_IN
  const long M = (long)in_sizes[0] / K;  // B*S

  const size_t need = ((size_t)M * K + (size_t)N * K) * sizeof(unsigned short);
  const long NT = K / 64;
  const bool ok = (ws_size >= need) && (M % 256 == 0) && (N % 256 == 0) &&
                  (K % 128 == 0) && (NT >= 4);

  if (ok) {
    unsigned short* xa = (unsigned short*)d_ws;
    unsigned short* wb = xa + (size_t)M * K;
    int n8x = (int)((size_t)M * K / 8);
    int n8w = (int)((size_t)N * K / 8);
    cvt_xw_kernel<<<2048, 256, 0, stream>>>(x, w, scale, (ushort8*)xa, (ushort8*)wb,
                                            n8x, n8w, (int)(K / 8));

    (void)hipFuncSetAttribute((const void*)gemm256_16w,
                              hipFuncAttributeMaxDynamicSharedMemorySize, 131072);
    int nwg = (int)((M / 256) * (N / 256));
    gemm256_16w<<<nwg, 1024, 131072, stream>>>(xa, wb, bias, out, (int)M, (int)N, (int)K);
  } else {
    dim3 grid((unsigned)((N + 63) / 64), (unsigned)((M + 63) / 64));
    gemm_fallback_kernel<<<grid, 256, 0, stream>>>(x, w, scale, bias, out, (int)M, (int)N, (int)K);
  }
}

// Round 19
// 164.587 us; speedup vs baseline: 1.5992x; 1.5992x over previous
//
#include <hip/hip_runtime.h>

typedef __attribute__((ext_vector_type(8))) __bf16 bf16x8;
typedef __attribute__((ext_vector_type(4))) float f32x4;
typedef __attribute__((ext_vector_type(8))) unsigned short ushort8;
typedef const __attribute__((address_space(1))) unsigned int gq_t;
typedef __attribute__((address_space(3))) unsigned int lq_t;

// RNE float -> bf16 (finite inputs)
__device__ __forceinline__ unsigned short f2bf(float f) {
  unsigned int u = __builtin_bit_cast(unsigned int, f);
  u += 0x7fffu + ((u >> 16) & 1u);
  return (unsigned short)(u >> 16);
}

// ------- fused convert: x -> bf16 and weight*scale -> bf16, one dispatch -------
__global__ void cvt_xw_kernel(const float* __restrict__ x, const float* __restrict__ w,
                              const float* __restrict__ scale,
                              ushort8* __restrict__ xa, ushort8* __restrict__ wb,
                              int n8x, int n8w, int k8) {
  int stride = gridDim.x * blockDim.x;
  int total = n8x + n8w;
  for (int i = blockIdx.x * blockDim.x + threadIdx.x; i < total; i += stride) {
    if (i < n8x) {
      const float4* p = (const float4*)(x) + 2 * (size_t)i;
      float4 v0 = p[0], v1 = p[1];
      ushort8 r;
      r[0] = f2bf(v0.x); r[1] = f2bf(v0.y); r[2] = f2bf(v0.z); r[3] = f2bf(v0.w);
      r[4] = f2bf(v1.x); r[5] = f2bf(v1.y); r[6] = f2bf(v1.z); r[7] = f2bf(v1.w);
      xa[i] = r;
    } else {
      int j = i - n8x;
      float s = scale[j / k8];
      const float4* p = (const float4*)(w) + 2 * (size_t)j;
      float4 v0 = p[0], v1 = p[1];
      ushort8 r;
      r[0] = f2bf(v0.x * s); r[1] = f2bf(v0.y * s); r[2] = f2bf(v0.z * s); r[3] = f2bf(v0.w * s);
      r[4] = f2bf(v1.x * s); r[5] = f2bf(v1.y * s); r[6] = f2bf(v1.z * s); r[7] = f2bf(v1.w * s);
      wb[j] = r;
    }
  }
}

// =================== 256x256 4-barrier/K-tile GEMM (FINAL: measured best) ===================
// C = A * B^T + bias.  A: bf16 [M][K], B: bf16 [N][K], C: fp32 [M][N].
// 8 waves (2 wr x 4 wc), BK=64, 128 KiB dynamic LDS.
//   buffer (64 KiB): [Amh0 16K][Amh1 16K][Bnh0 16K][Bnh1 16K], tile parity picks buffer.
// ONE barrier per phase (between {ds_reads, GL stage} and QUAD) — no end-of-phase
// barrier, so waves STAGGER. Measured best of the 18-round search family
// (138.7-140us GEMM = 988 TF, MfmaUtil 43.5, conflicts 0, FETCH ~100MB; total
// 164.4-164.7us, twice reproduced).
// Search ledger (single-variable A/Bs): 8-barrier lockstep −10%; 2-barrier merge
// −50%; depth-3 vmcnt null; MFMA order null; mem-op weaving −57%; BK=32 null;
// no-swizzle FETCH 100->272MB; col-major FETCH 100->276MB; LDB1 one-ahead −32%
// (12-read pre-barrier burst kills stagger; 8/4/8/0 balance is load-bearing);
// 16-wave 64x64/wave: occupancy 21->41% but MfmaUtil 43.6->21.8 (wider lockstep,
// halved per-phase MFMA window, write amplification) — occupancy is NOT the lever.
// Deadness audit: each staged region's old readers lgkm-complete >=1 full phase +
// barrier before the overwriting GL issues:
//   P1->ob.Bnh0 (old read t-2.P4-tail), P2->ob.Amh1 (old read t-1.P3),
//   P3->cb.Amh0 (old read t.P1), P4->cb.Bnh1 (old read t.P2).
// vmcnt ledger (FIFO, 2 loads/unit): WAITV4 at P4 retires exactly tile t+1's 4
// units (wait distance 3-4 phases, zero-stall per R8 depth-3 null); WAITV0 at NT-2.
// XOR swizzle byte ^= ((row&7)<<4): pre-swizzled global source + swizzled reads.
// global_load_lds offset immediate applies to LDS dest too -> ALWAYS offset=0;
// K-advance lives in 8 running pointers (pre-led 1 or 2 tiles), +64 elems/tile.

#define BARRIER asm volatile("s_barrier" ::: "memory")
#define WAITV4 asm volatile("s_waitcnt vmcnt(4)" ::: "memory")
#define WAITV0 asm volatile("s_waitcnt vmcnt(0)" ::: "memory")
#define GL(p, d) __builtin_amdgcn_global_load_lds((gq_t*)(p), (lq_t*)(d), 16, 0, 0)

#define QUAD(MH, BG, NHB)                                                                \
  do {                                                                                   \
    __builtin_amdgcn_s_setprio(1);                                                       \
    _Pragma("unroll") for (int k_ = 0; k_ < 2; ++k_) {                                   \
      _Pragma("unroll") for (int mm = 0; mm < 4; ++mm) {                                 \
        _Pragma("unroll") for (int nn = 0; nn < 2; ++nn) {                               \
          acc[(MH)*4 + mm][(NHB)*2 + nn] = __builtin_amdgcn_mfma_f32_16x16x32_bf16(      \
              af[mm][k_], BG[nn][k_], acc[(MH)*4 + mm][(NHB)*2 + nn], 0, 0, 0);          \
        }                                                                                \
      }                                                                                  \
    }                                                                                    \
    __builtin_amdgcn_s_setprio(0);                                                       \
  } while (0)

#define TILE_BODY(T, CB)                                                                 \
  do {                                                                                   \
    const int t_ = (T);                                                                  \
    char* cur = lds + (CB) * 65536;                                                      \
    char* oth = lds + (((CB) ^ 1)) * 65536;                                              \
    /* P1: reads Amh0 (8 ds_read) ; stages Bn01(t+1) -> ob.Bnh0 */                       \
    LDA(cur, 0);                                                                         \
    if (t_ + 1 < NT) { GL(bP0lo, oth + 32768 + dstT);                                    \
                       GL(bP0hi, oth + 32768 + 8192 + dstT); }                           \
    BARRIER; QUAD(0, bg0, 0);                                                            \
    /* P2: reads Bnh1 (4) ; stages Am47(t+1) -> ob.Amh1 */                               \
    LDB1(cur);                                                                           \
    if (t_ + 1 < NT) { GL(aP1lo, oth + 16384 + dstT);                                    \
                       GL(aP1hi, oth + 16384 + 8192 + dstT); }                           \
    BARRIER; QUAD(0, bg1, 1);                                                            \
    /* P3: reads Amh1 (8) ; stages Am03(t+2) -> cb.Amh0 */                               \
    LDA(cur, 1);                                                                         \
    if (t_ + 2 < NT) { GL(aP0lo, cur + dstT);                                            \
                       GL(aP0hi, cur + 8192 + dstT); }                                   \
    BARRIER; QUAD(1, bg1, 1);                                                            \
    /* P4: stages Bn23(t+2) -> cb.Bnh1 ; wait ; BAR ; QUAD ; prefetch next Bnh0 (4) */   \
    if (t_ + 2 < NT) { GL(bP1lo, cur + 49152 + dstT);                                    \
                       GL(bP1hi, cur + 49152 + 8192 + dstT); }                           \
    if (t_ == NT - 2) { WAITV0; } else { WAITV4; }                                       \
    BARRIER; QUAD(1, bg0, 0);                                                            \
    if (t_ + 1 < NT) LDB0(oth);                                                          \
    aP0lo += 64; aP0hi += 64; aP1lo += 64; aP1hi += 64;                                  \
    bP0lo += 64; bP0hi += 64; bP1lo += 64; bP1hi += 64;                                  \
  } while (0)

__global__ __launch_bounds__(512, 2) void gemm256_8ph(
    const unsigned short* __restrict__ A, const unsigned short* __restrict__ B,
    const float* __restrict__ bias, float* __restrict__ C, int M, int N, int K) {
  extern __shared__ char lds[];

  const int nbn = N >> 8;
  const int nwg = (M >> 8) * nbn;
  int bid = blockIdx.x;
  if ((nwg & 7) == 0) {  // XCD-aware swizzle (bijective when nwg%8==0)
    int q = nwg >> 3;
    bid = (bid & 7) * q + (bid >> 3);
  }
  const int bm = (bid / nbn) << 8;   // ROW-major within chunk (col-major thrashes A in L2)
  const int bn = (bid % nbn) << 8;

  const int tid = threadIdx.x;
  const int lane = tid & 63;
  const int wid = tid >> 6;
  const int wr = wid >> 2;  // 0..1
  const int wc = wid & 3;   // 0..3
  const int NT = K >> 6;    // K-tiles of 64
  const int dstT = tid * 16;

  // ---- pre-swizzled global sources (rule 21: linear LDS dest + inv-swz source) ----
  // phys row within unit = tid>>3 ; logical col = ((tid&7) ^ ((tid>>3)&7)) * 8 elems
  const int colel = (((tid & 7) ^ ((tid >> 3) & 7)) << 3);
  const unsigned short* aBase = A + (size_t)(bm + (tid >> 3)) * K + colel;
  const unsigned short* bBase = B + (size_t)(bn + ((tid >> 8) << 6) + ((tid >> 3) & 31)) * K + colel;
  const unsigned short* aP0lo = aBase;                    // Amh0 rows 0-63
  const unsigned short* aP0hi = aBase + (size_t)128 * K;  // Amh0 rows 128-191
  const unsigned short* aP1lo = aBase + (size_t)64 * K;   // Amh1 rows 64-127
  const unsigned short* aP1hi = aBase + (size_t)192 * K;  // Amh1 rows 192-255
  const unsigned short* bP0lo = bBase;                    // Bnh0
  const unsigned short* bP0hi = bBase + (size_t)128 * K;
  const unsigned short* bP1lo = bBase + (size_t)32 * K;   // Bnh1
  const unsigned short* bP1hi = bBase + (size_t)160 * K;

  // ---- fragment read offsets (swizzled) ----
  const int i15 = lane & 15;
  const int qg = lane >> 4;
  const int swz = (lane & 7) << 4;
  const int colp0 = (qg << 4) ^ swz;
  const int colp1 = ((qg << 4) | 64) ^ swz;
  const int aoff = wr * 8192 + i15 * 128;
  const int boff = 32768 + wc * 4096 + i15 * 128;

  f32x4 acc[8][4];
#pragma unroll
  for (int m = 0; m < 8; ++m)
#pragma unroll
    for (int n = 0; n < 4; ++n) acc[m][n] = (f32x4){0.f, 0.f, 0.f, 0.f};

  bf16x8 af[4][2];   // current A half [mm][kk]
  bf16x8 bg0[2][2];  // Bnh0 fragments (prefetched one tile ahead)
  bf16x8 bg1[2][2];  // Bnh1 fragments (current tile)

  auto LDA = [&](const char* base, int mh) {
    const char* p = base + mh * 16384 + aoff;
#pragma unroll
    for (int mm = 0; mm < 4; ++mm) {
      af[mm][0] = *(const bf16x8*)(p + mm * 2048 + colp0);
      af[mm][1] = *(const bf16x8*)(p + mm * 2048 + colp1);
    }
  };
  auto LDB0 = [&](const char* base) {  // Bnh0 -> bg0
    const char* p = base + boff;
#pragma unroll
    for (int nn = 0; nn < 2; ++nn) {
      bg0[nn][0] = *(const bf16x8*)(p + nn * 2048 + colp0);
      bg0[nn][1] = *(const bf16x8*)(p + nn * 2048 + colp1);
    }
  };
  auto LDB1 = [&](const char* base) {  // Bnh1 -> bg1
    const char* p = base + 16384 + boff;
#pragma unroll
    for (int nn = 0; nn < 2; ++nn) {
      bg1[nn][0] = *(const bf16x8*)(p + nn * 2048 + colp0);
      bg1[nn][1] = *(const bf16x8*)(p + nn * 2048 + colp1);
    }
  };

  // ---- prologue: tile0's 4 units, then tile1's {Amh0, Bnh1} into buf1 ----
  GL(aP0lo, lds + dstT);                     GL(aP0hi, lds + 8192 + dstT);
  GL(bP1lo, lds + 49152 + dstT);             GL(bP1hi, lds + 49152 + 8192 + dstT);
  GL(bP0lo, lds + 32768 + dstT);             GL(bP0hi, lds + 32768 + 8192 + dstT);
  GL(aP1lo, lds + 16384 + dstT);             GL(aP1hi, lds + 16384 + 8192 + dstT);
  GL(aP0lo + 64, lds + 65536 + dstT);        GL(aP0hi + 64, lds + 65536 + 8192 + dstT);
  GL(bP1lo + 64, lds + 65536 + 49152 + dstT);
  GL(bP1hi + 64, lds + 65536 + 49152 + 8192 + dstT);
  WAITV4;   // retire tile0's 8 loads; tile1's {Am03,Bn23} stay in flight
  BARRIER;  // all waves' tile0 stages visible
  LDB0(lds);  // bg0 <- buf0.Bnh0 (tile0)
  // apply leads: P1/P2-staged units lead by 1 tile, P3/P4 units by 2 tiles
  bP0lo += 64;  bP0hi += 64;  aP1lo += 64;  aP1hi += 64;
  aP0lo += 128; aP0hi += 128; bP1lo += 128; bP1hi += 128;

  // ---- main loop: 2 tiles per iteration (compile-time buffer parity) ----
  for (int t = 0; t < NT; t += 2) {
    TILE_BODY(t, 0);
    TILE_BODY(t + 1, 1);
  }

  // ---- epilogue: C/D map col=lane&15, row=(lane>>4)*4+reg ----
  const int r0 = bm + wr * 128 + ((lane >> 4) << 2);
  const int c0 = bn + wc * 64 + (lane & 15);
  float bv[4];
#pragma unroll
  for (int n = 0; n < 4; ++n) bv[n] = bias[c0 + n * 16];
#pragma unroll
  for (int m = 0; m < 8; ++m) {
#pragma unroll
    for (int r = 0; r < 4; ++r) {
      float* crow = C + (size_t)(r0 + m * 16 + r) * N + c0;
#pragma unroll
      for (int n = 0; n < 4; ++n) crow[n * 16] = acc[m][n][r] + bv[n];
    }
  }
}

// ---------- fallback: fp32 tiled (odd shapes / tiny ws) ----------
__global__ void gemm_fallback_kernel(const float* __restrict__ X, const float* __restrict__ W,
                                     const float* __restrict__ scale, const float* __restrict__ bias,
                                     float* __restrict__ out, int M, int N, int K) {
  __shared__ float as[64][33];
  __shared__ float bs[64][33];
  int tx = threadIdx.x & 15, ty = threadIdx.x >> 4;
  int brow = blockIdx.y * 64, bcol = blockIdx.x * 64;
  float acc[4][4] = {};
  for (int k0 = 0; k0 < K; k0 += 32) {
    int kw = (K - k0 < 32) ? (K - k0) : 32;
    for (int i = 0; i < 8; ++i) {
      int idx = (int)threadIdx.x + i * 256;
      int r = idx >> 5, c = idx & 31;
      int ga = brow + r, gb = bcol + r;
      as[r][c] = (ga < M && c < kw) ? X[(size_t)ga * K + k0 + c] : 0.f;
      bs[r][c] = (gb < N && c < kw) ? W[(size_t)gb * K + k0 + c] * scale[gb] : 0.f;
    }
    __syncthreads();
    for (int k = 0; k < 32; ++k)
#pragma unroll
      for (int i = 0; i < 4; ++i)
#pragma unroll
        for (int j = 0; j < 4; ++j)
          acc[i][j] += as[ty * 4 + i][k] * bs[tx * 4 + j][k];
    __syncthreads();
  }
  for (int i = 0; i < 4; ++i) {
    int r = brow + ty * 4 + i;
    if (r >= M) continue;
    for (int j = 0; j < 4; ++j) {
      int c = bcol + tx * 4 + j;
      if (c < N) out[(size_t)r * N + c] = acc[i][j] + bias[c];
    }
  }
}

extern "C" void kernel_launch(void* const* d_in, const int* in_sizes, int n_in,
                              void* d_out, int out_size, void* d_ws, size_t ws_size,
                              hipStream_t stream) {
  const float* x     = (const float*)d_in[0];
  const float* w     = (const float*)d_in[1];
  const float* scale = (const float*)d_in[2];
  const float* bias  = (const float*)d_in[3];
  float* out = (float*)d_out;

  const long N = in_sizes[2];            // D_OUT
  const long K = in_sizes[1] / N;        // D_IN
  const long M = (long)in_sizes[0] / K;  // B*S

  const size_t need = ((size_t)M * K + (size_t)N * K) * sizeof(unsigned short);
  const long NT = K / 64;
  const bool ok = (ws_size >= need) && (M % 256 == 0) && (N % 256 == 0) &&
                  (K % 128 == 0) && (NT >= 4);

  if (ok) {
    unsigned short* xa = (unsigned short*)d_ws;
    unsigned short* wb = xa + (size_t)M * K;
    int n8x = (int)((size_t)M * K / 8);
    int n8w = (int)((size_t)N * K / 8);
    cvt_xw_kernel<<<2048, 256, 0, stream>>>(x, w, scale, (ushort8*)xa, (ushort8*)wb,
                                            n8x, n8w, (int)(K / 8));

    (void)hipFuncSetAttribute((const void*)gemm256_8ph,
                              hipFuncAttributeMaxDynamicSharedMemorySize, 131072);
    int nwg = (int)((M / 256) * (N / 256));
    gemm256_8ph<<<nwg, 512, 131072, stream>>>(xa, wb, bias, out, (int)M, (int)N, (int)K);
  } else {
    dim3 grid((unsigned)((N + 63) / 64), (unsigned)((M + 63) / 64));
    gemm_fallback_kernel<<<grid, 256, 0, stream>>>(x, w, scale, bias, out, (int)M, (int)N, (int)K);
  }
}

// Round 20
// 164.161 us; speedup vs baseline: 1.6034x; 1.0026x over previous
//
#include <hip/hip_runtime.h>

typedef __attribute__((ext_vector_type(8))) __bf16 bf16x8;
typedef __attribute__((ext_vector_type(4))) float f32x4;
typedef __attribute__((ext_vector_type(8))) unsigned short ushort8;
typedef const __attribute__((address_space(1))) unsigned int gq_t;
typedef __attribute__((address_space(3))) unsigned int lq_t;

// RNE float -> bf16 (finite inputs)
__device__ __forceinline__ unsigned short f2bf(float f) {
  unsigned int u = __builtin_bit_cast(unsigned int, f);
  u += 0x7fffu + ((u >> 16) & 1u);
  return (unsigned short)(u >> 16);
}

// ------- fused convert: x -> bf16 and weight*scale -> bf16, one dispatch -------
__global__ void cvt_xw_kernel(const float* __restrict__ x, const float* __restrict__ w,
                              const float* __restrict__ scale,
                              ushort8* __restrict__ xa, ushort8* __restrict__ wb,
                              int n8x, int n8w, int k8) {
  int stride = gridDim.x * blockDim.x;
  int total = n8x + n8w;
  for (int i = blockIdx.x * blockDim.x + threadIdx.x; i < total; i += stride) {
    if (i < n8x) {
      const float4* p = (const float4*)(x) + 2 * (size_t)i;
      float4 v0 = p[0], v1 = p[1];
      ushort8 r;
      r[0] = f2bf(v0.x); r[1] = f2bf(v0.y); r[2] = f2bf(v0.z); r[3] = f2bf(v0.w);
      r[4] = f2bf(v1.x); r[5] = f2bf(v1.y); r[6] = f2bf(v1.z); r[7] = f2bf(v1.w);
      xa[i] = r;
    } else {
      int j = i - n8x;
      float s = scale[j / k8];
      const float4* p = (const float4*)(w) + 2 * (size_t)j;
      float4 v0 = p[0], v1 = p[1];
      ushort8 r;
      r[0] = f2bf(v0.x * s); r[1] = f2bf(v0.y * s); r[2] = f2bf(v0.z * s); r[3] = f2bf(v0.w * s);
      r[4] = f2bf(v1.x * s); r[5] = f2bf(v1.y * s); r[6] = f2bf(v1.z * s); r[7] = f2bf(v1.w * s);
      wb[j] = r;
    }
  }
}

// =================== 256x256 4-barrier/K-tile GEMM (FINAL: measured best) ===================
// C = A * B^T + bias.  A: bf16 [M][K], B: bf16 [N][K], C: fp32 [M][N].
// 8 waves (2 wr x 4 wc), BK=64, 128 KiB dynamic LDS.
//   buffer (64 KiB): [Amh0 16K][Amh1 16K][Bnh0 16K][Bnh1 16K], tile parity picks buffer.
// ONE barrier per phase (between {ds_reads, GL stage} and QUAD) — no end-of-phase
// barrier, so waves STAGGER. Measured best of the 19-round search family
// (138.7-140us GEMM = 988 TF, MfmaUtil 43.5, conflicts 0, FETCH ~100MB; total
// 164.4-164.7us, three times reproduced).
// Search ledger (single-variable A/Bs): 8-barrier lockstep −10%; 2-barrier merge
// −50%; depth-3 vmcnt null; MFMA order null; mem-op weaving −57%; BK=32 null;
// no-swizzle FETCH 100->272MB; col-major FETCH 100->276MB; LDB1 one-ahead −32%
// (12-read pre-barrier burst kills stagger; 8/4/8/0 balance is load-bearing);
// 16-wave 64x64/wave: occupancy 21->41% but MfmaUtil 43.6->21.8 (wider lockstep,
// halved per-phase MFMA window, write amplification) — occupancy is NOT the lever.
// Deadness audit: each staged region's old readers lgkm-complete >=1 full phase +
// barrier before the overwriting GL issues:
//   P1->ob.Bnh0 (old read t-2.P4-tail), P2->ob.Amh1 (old read t-1.P3),
//   P3->cb.Amh0 (old read t.P1), P4->cb.Bnh1 (old read t.P2).
// vmcnt ledger (FIFO, 2 loads/unit): WAITV4 at P4 retires exactly tile t+1's 4
// units (wait distance 3-4 phases, zero-stall per R8 depth-3 null); WAITV0 at NT-2.
// XOR swizzle byte ^= ((row&7)<<4): pre-swizzled global source + swizzled reads.
// global_load_lds offset immediate applies to LDS dest too -> ALWAYS offset=0;
// K-advance lives in 8 running pointers (pre-led 1 or 2 tiles), +64 elems/tile.

#define BARRIER asm volatile("s_barrier" ::: "memory")
#define WAITV4 asm volatile("s_waitcnt vmcnt(4)" ::: "memory")
#define WAITV0 asm volatile("s_waitcnt vmcnt(0)" ::: "memory")
#define GL(p, d) __builtin_amdgcn_global_load_lds((gq_t*)(p), (lq_t*)(d), 16, 0, 0)

#define QUAD(MH, BG, NHB)                                                                \
  do {                                                                                   \
    __builtin_amdgcn_s_setprio(1);                                                       \
    _Pragma("unroll") for (int k_ = 0; k_ < 2; ++k_) {                                   \
      _Pragma("unroll") for (int mm = 0; mm < 4; ++mm) {                                 \
        _Pragma("unroll") for (int nn = 0; nn < 2; ++nn) {                               \
          acc[(MH)*4 + mm][(NHB)*2 + nn] = __builtin_amdgcn_mfma_f32_16x16x32_bf16(      \
              af[mm][k_], BG[nn][k_], acc[(MH)*4 + mm][(NHB)*2 + nn], 0, 0, 0);          \
        }                                                                                \
      }                                                                                  \
    }                                                                                    \
    __builtin_amdgcn_s_setprio(0);                                                       \
  } while (0)

#define TILE_BODY(T, CB)                                                                 \
  do {                                                                                   \
    const int t_ = (T);                                                                  \
    char* cur = lds + (CB) * 65536;                                                      \
    char* oth = lds + (((CB) ^ 1)) * 65536;                                              \
    /* P1: reads Amh0 (8 ds_read) ; stages Bn01(t+1) -> ob.Bnh0 */                       \
    LDA(cur, 0);                                                                         \
    if (t_ + 1 < NT) { GL(bP0lo, oth + 32768 + dstT);                                    \
                       GL(bP0hi, oth + 32768 + 8192 + dstT); }                           \
    BARRIER; QUAD(0, bg0, 0);                                                            \
    /* P2: reads Bnh1 (4) ; stages Am47(t+1) -> ob.Amh1 */                               \
    LDB1(cur);                                                                           \
    if (t_ + 1 < NT) { GL(aP1lo, oth + 16384 + dstT);                                    \
                       GL(aP1hi, oth + 16384 + 8192 + dstT); }                           \
    BARRIER; QUAD(0, bg1, 1);                                                            \
    /* P3: reads Amh1 (8) ; stages Am03(t+2) -> cb.Amh0 */                               \
    LDA(cur, 1);                                                                         \
    if (t_ + 2 < NT) { GL(aP0lo, cur + dstT);                                            \
                       GL(aP0hi, cur + 8192 + dstT); }                                   \
    BARRIER; QUAD(1, bg1, 1);                                                            \
    /* P4: stages Bn23(t+2) -> cb.Bnh1 ; wait ; BAR ; QUAD ; prefetch next Bnh0 (4) */   \
    if (t_ + 2 < NT) { GL(bP1lo, cur + 49152 + dstT);                                    \
                       GL(bP1hi, cur + 49152 + 8192 + dstT); }                           \
    if (t_ == NT - 2) { WAITV0; } else { WAITV4; }                                       \
    BARRIER; QUAD(1, bg0, 0);                                                            \
    if (t_ + 1 < NT) LDB0(oth);                                                          \
    aP0lo += 64; aP0hi += 64; aP1lo += 64; aP1hi += 64;                                  \
    bP0lo += 64; bP0hi += 64; bP1lo += 64; bP1hi += 64;                                  \
  } while (0)

__global__ __launch_bounds__(512, 2) void gemm256_8ph(
    const unsigned short* __restrict__ A, const unsigned short* __restrict__ B,
    const float* __restrict__ bias, float* __restrict__ C, int M, int N, int K) {
  extern __shared__ char lds[];

  const int nbn = N >> 8;
  const int nwg = (M >> 8) * nbn;
  int bid = blockIdx.x;
  if ((nwg & 7) == 0) {  // XCD-aware swizzle (bijective when nwg%8==0)
    int q = nwg >> 3;
    bid = (bid & 7) * q + (bid >> 3);
  }
  const int bm = (bid / nbn) << 8;   // ROW-major within chunk (col-major thrashes A in L2)
  const int bn = (bid % nbn) << 8;

  const int tid = threadIdx.x;
  const int lane = tid & 63;
  const int wid = tid >> 6;
  const int wr = wid >> 2;  // 0..1
  const int wc = wid & 3;   // 0..3
  const int NT = K >> 6;    // K-tiles of 64
  const int dstT = tid * 16;

  // ---- pre-swizzled global sources (rule 21: linear LDS dest + inv-swz source) ----
  // phys row within unit = tid>>3 ; logical col = ((tid&7) ^ ((tid>>3)&7)) * 8 elems
  const int colel = (((tid & 7) ^ ((tid >> 3) & 7)) << 3);
  const unsigned short* aBase = A + (size_t)(bm + (tid >> 3)) * K + colel;
  const unsigned short* bBase = B + (size_t)(bn + ((tid >> 8) << 6) + ((tid >> 3) & 31)) * K + colel;
  const unsigned short* aP0lo = aBase;                    // Amh0 rows 0-63
  const unsigned short* aP0hi = aBase + (size_t)128 * K;  // Amh0 rows 128-191
  const unsigned short* aP1lo = aBase + (size_t)64 * K;   // Amh1 rows 64-127
  const unsigned short* aP1hi = aBase + (size_t)192 * K;  // Amh1 rows 192-255
  const unsigned short* bP0lo = bBase;                    // Bnh0
  const unsigned short* bP0hi = bBase + (size_t)128 * K;
  const unsigned short* bP1lo = bBase + (size_t)32 * K;   // Bnh1
  const unsigned short* bP1hi = bBase + (size_t)160 * K;

  // ---- fragment read offsets (swizzled) ----
  const int i15 = lane & 15;
  const int qg = lane >> 4;
  const int swz = (lane & 7) << 4;
  const int colp0 = (qg << 4) ^ swz;
  const int colp1 = ((qg << 4) | 64) ^ swz;
  const int aoff = wr * 8192 + i15 * 128;
  const int boff = 32768 + wc * 4096 + i15 * 128;

  f32x4 acc[8][4];
#pragma unroll
  for (int m = 0; m < 8; ++m)
#pragma unroll
    for (int n = 0; n < 4; ++n) acc[m][n] = (f32x4){0.f, 0.f, 0.f, 0.f};

  bf16x8 af[4][2];   // current A half [mm][kk]
  bf16x8 bg0[2][2];  // Bnh0 fragments (prefetched one tile ahead)
  bf16x8 bg1[2][2];  // Bnh1 fragments (current tile)

  auto LDA = [&](const char* base, int mh) {
    const char* p = base + mh * 16384 + aoff;
#pragma unroll
    for (int mm = 0; mm < 4; ++mm) {
      af[mm][0] = *(const bf16x8*)(p + mm * 2048 + colp0);
      af[mm][1] = *(const bf16x8*)(p + mm * 2048 + colp1);
    }
  };
  auto LDB0 = [&](const char* base) {  // Bnh0 -> bg0
    const char* p = base + boff;
#pragma unroll
    for (int nn = 0; nn < 2; ++nn) {
      bg0[nn][0] = *(const bf16x8*)(p + nn * 2048 + colp0);
      bg0[nn][1] = *(const bf16x8*)(p + nn * 2048 + colp1);
    }
  };
  auto LDB1 = [&](const char* base) {  // Bnh1 -> bg1
    const char* p = base + 16384 + boff;
#pragma unroll
    for (int nn = 0; nn < 2; ++nn) {
      bg1[nn][0] = *(const bf16x8*)(p + nn * 2048 + colp0);
      bg1[nn][1] = *(const bf16x8*)(p + nn * 2048 + colp1);
    }
  };

  // ---- prologue: tile0's 4 units, then tile1's {Amh0, Bnh1} into buf1 ----
  GL(aP0lo, lds + dstT);                     GL(aP0hi, lds + 8192 + dstT);
  GL(bP1lo, lds + 49152 + dstT);             GL(bP1hi, lds + 49152 + 8192 + dstT);
  GL(bP0lo, lds + 32768 + dstT);             GL(bP0hi, lds + 32768 + 8192 + dstT);
  GL(aP1lo, lds + 16384 + dstT);             GL(aP1hi, lds + 16384 + 8192 + dstT);
  GL(aP0lo + 64, lds + 65536 + dstT);        GL(aP0hi + 64, lds + 65536 + 8192 + dstT);
  GL(bP1lo + 64, lds + 65536 + 49152 + dstT);
  GL(bP1hi + 64, lds + 65536 + 49152 + 8192 + dstT);
  WAITV4;   // retire tile0's 8 loads; tile1's {Am03,Bn23} stay in flight
  BARRIER;  // all waves' tile0 stages visible
  LDB0(lds);  // bg0 <- buf0.Bnh0 (tile0)
  // apply leads: P1/P2-staged units lead by 1 tile, P3/P4 units by 2 tiles
  bP0lo += 64;  bP0hi += 64;  aP1lo += 64;  aP1hi += 64;
  aP0lo += 128; aP0hi += 128; bP1lo += 128; bP1hi += 128;

  // ---- main loop: 2 tiles per iteration (compile-time buffer parity) ----
  for (int t = 0; t < NT; t += 2) {
    TILE_BODY(t, 0);
    TILE_BODY(t + 1, 1);
  }

  // ---- epilogue: C/D map col=lane&15, row=(lane>>4)*4+reg ----
  const int r0 = bm + wr * 128 + ((lane >> 4) << 2);
  const int c0 = bn + wc * 64 + (lane & 15);
  float bv[4];
#pragma unroll
  for (int n = 0; n < 4; ++n) bv[n] = bias[c0 + n * 16];
#pragma unroll
  for (int m = 0; m < 8; ++m) {
#pragma unroll
    for (int r = 0; r < 4; ++r) {
      float* crow = C + (size_t)(r0 + m * 16 + r) * N + c0;
#pragma unroll
      for (int n = 0; n < 4; ++n) crow[n * 16] = acc[m][n][r] + bv[n];
    }
  }
}

// ---------- fallback: fp32 tiled (odd shapes / tiny ws) ----------
__global__ void gemm_fallback_kernel(const float* __restrict__ X, const float* __restrict__ W,
                                     const float* __restrict__ scale, const float* __restrict__ bias,
                                     float* __restrict__ out, int M, int N, int K) {
  __shared__ float as[64][33];
  __shared__ float bs[64][33];
  int tx = threadIdx.x & 15, ty = threadIdx.x >> 4;
  int brow = blockIdx.y * 64, bcol = blockIdx.x * 64;
  float acc[4][4] = {};
  for (int k0 = 0; k0 < K; k0 += 32) {
    int kw = (K - k0 < 32) ? (K - k0) : 32;
    for (int i = 0; i < 8; ++i) {
      int idx = (int)threadIdx.x + i * 256;
      int r = idx >> 5, c = idx & 31;
      int ga = brow + r, gb = bcol + r;
      as[r][c] = (ga < M && c < kw) ? X[(size_t)ga * K + k0 + c] : 0.f;
      bs[r][c] = (gb < N && c < kw) ? W[(size_t)gb * K + k0 + c] * scale[gb] : 0.f;
    }
    __syncthreads();
    for (int k = 0; k < 32; ++k)
#pragma unroll
      for (int i = 0; i < 4; ++i)
#pragma unroll
        for (int j = 0; j < 4; ++j)
          acc[i][j] += as[ty * 4 + i][k] * bs[tx * 4 + j][k];
    __syncthreads();
  }
  for (int i = 0; i < 4; ++i) {
    int r = brow + ty * 4 + i;
    if (r >= M) continue;
    for (int j = 0; j < 4; ++j) {
      int c = bcol + tx * 4 + j;
      if (c < N) out[(size_t)r * N + c] = acc[i][j] + bias[c];
    }
  }
}

extern "C" void kernel_launch(void* const* d_in, const int* in_sizes, int n_in,
                              void* d_out, int out_size, void* d_ws, size_t ws_size,
                              hipStream_t stream) {
  const float* x     = (const float*)d_in[0];
  const float* w     = (const float*)d_in[1];
  const float* scale = (const float*)d_in[2];
  const float* bias  = (const float*)d_in[3];
  float* out = (float*)d_out;

  const long N = in_sizes[2];            // D_OUT
  const long K = in_sizes[1] / N;        // D_IN
  const long M = (long)in_sizes[0] / K;  // B*S

  const size_t need = ((size_t)M * K + (size_t)N * K) * sizeof(unsigned short);
  const long NT = K / 64;
  const bool ok = (ws_size >= need) && (M % 256 == 0) && (N % 256 == 0) &&
                  (K % 128 == 0) && (NT >= 4);

  if (ok) {
    unsigned short* xa = (unsigned short*)d_ws;
    unsigned short* wb = xa + (size_t)M * K;
    int n8x = (int)((size_t)M * K / 8);
    int n8w = (int)((size_t)N * K / 8);
    cvt_xw_kernel<<<2048, 256, 0, stream>>>(x, w, scale, (ushort8*)xa, (ushort8*)wb,
                                            n8x, n8w, (int)(K / 8));

    (void)hipFuncSetAttribute((const void*)gemm256_8ph,
                              hipFuncAttributeMaxDynamicSharedMemorySize, 131072);
    int nwg = (int)((M / 256) * (N / 256));
    gemm256_8ph<<<nwg, 512, 131072, stream>>>(xa, wb, bias, out, (int)M, (int)N, (int)K);
  } else {
    dim3 grid((unsigned)((N + 63) / 64), (unsigned)((M + 63) / 64));
    gemm_fallback_kernel<<<grid, 256, 0, stream>>>(x, w, scale, bias, out, (int)M, (int)N, (int)K);
  }
}